// Round 1
// baseline (131.981 us; speedup 1.0000x reference)
//
#include <hip/hip_runtime.h>

// CostVolume: out[b,c,d,h,w] = left[b,c,h,w] * right[b,c,h,w-d] if w>=d else 0,
// clipped to +-1000. B=1, C=32, H=160, W=320, D=64 (fixed by setup_inputs).
// Output f32: 32*64*160*320 = 104,857,600 elems = 419.4 MB -> write-BW-bound.

constexpr float CLAMPV = 1000.0f;
constexpr int C  = 32;
constexpr int H  = 160;
constexpr int W  = 320;
constexpr int W4 = W / 4;          // 80 float4 per row
constexpr int SLICE4 = H * W4;     // 12800 float4 per (c,d) slice
constexpr int BLOCK = 256;

__global__ __launch_bounds__(BLOCK) void costvol_kernel(
    const float* __restrict__ left,
    const float* __restrict__ right,
    float* __restrict__ out,
    int D)
{
    // blockIdx.y = c*D + d  (one (c,d) slice of H*W output elements)
    const int cd = blockIdx.y;
    const int d  = cd % D;         // uniform per block (scalar path)
    const int c  = cd / D;

    const int pos = blockIdx.x * BLOCK + threadIdx.x;   // float4 index in slice
    if (pos >= SLICE4) return;

    const int h = pos / W4;        // constant divisor -> magic multiply
    const int w = (pos - h * W4) * 4;

    const long rowoff = ((long)c * H + h) * W;
    const float4 l = *reinterpret_cast<const float4*>(left + rowoff + w);
    const float* rrow = right + rowoff;

    const int i0 = w - d;
    // Guarded scalar loads; inputs are 13 MB total -> L1/L2 hits.
    const float r0 = (i0     >= 0) ? rrow[i0]     : 0.0f;
    const float r1 = (i0 + 1 >= 0) ? rrow[i0 + 1] : 0.0f;
    const float r2 = (i0 + 2 >= 0) ? rrow[i0 + 2] : 0.0f;
    const float r3 = (i0 + 3 >= 0) ? rrow[i0 + 3] : 0.0f;

    float4 o;
    o.x = fminf(fmaxf(l.x * r0, -CLAMPV), CLAMPV);
    o.y = fminf(fmaxf(l.y * r1, -CLAMPV), CLAMPV);
    o.z = fminf(fmaxf(l.z * r2, -CLAMPV), CLAMPV);
    o.w = fminf(fmaxf(l.w * r3, -CLAMPV), CLAMPV);

    const long oidx = ((long)cd * H + h) * W + w;
    *reinterpret_cast<float4*>(out + oidx) = o;
}

extern "C" void kernel_launch(void* const* d_in, const int* in_sizes, int n_in,
                              void* d_out, int out_size, void* d_ws, size_t ws_size,
                              hipStream_t stream) {
    const float* left  = (const float*)d_in[0];
    const float* right = (const float*)d_in[1];
    float* out = (float*)d_out;

    // D = out_size / (B*C*H*W); with the fixed setup this is 64.
    const int D = out_size / in_sizes[0];
    const int slices = C * D;                       // gridDim.y = 2048
    const int blocks_per_slice = (SLICE4 + BLOCK - 1) / BLOCK;  // 50

    dim3 grid(blocks_per_slice, slices, 1);
    dim3 block(BLOCK, 1, 1);
    costvol_kernel<<<grid, block, 0, stream>>>(left, right, out, D);
}

// Round 3
// 83.571 us; speedup vs baseline: 1.5793x; 1.5793x over previous
//
#include <hip/hip_runtime.h>

// CostVolume: out[b,c,d,h,w] = left[b,c,h,w] * right[b,c,h,w-d] if w>=d else 0,
// clipped to +-1000. B=1, C=32, H=160, W=320, D=64 (runtime, from out_size).
// Output f32 = 419.4 MB -> streaming-write-bound. Inputs 13.1 MB total.
//
// Strategy: one block per (c,h) row pair. Stage left/right rows in LDS once
// (kills the 64x logical re-read of inputs that was round-tripping L2<->L3),
// then emit all D*W outputs of this row from LDS with coalesced float4
// nontemporal stores.

constexpr float CLAMPV = 1000.0f;
constexpr int C  = 32;
constexpr int H  = 160;
constexpr int W  = 320;
constexpr int W4 = W / 4;          // 80 float4 per row
constexpr int BLOCK = 256;

// Native vector type: __builtin_nontemporal_store requires a real vector,
// not HIP's struct-based float4.
typedef float fx4 __attribute__((ext_vector_type(4)));

__global__ __launch_bounds__(BLOCK) void costvol_kernel(
    const float* __restrict__ left,
    const float* __restrict__ right,
    float* __restrict__ out,
    int D)
{
    const int ch = blockIdx.x;         // c*H + h
    const int c  = ch / H;             // compile-time divisor -> magic mul
    const int h  = ch - c * H;

    __shared__ float sL[W];
    __shared__ float sR[W];

    const float* lrow = left  + (size_t)ch * W;
    const float* rrow = right + (size_t)ch * W;

    const int t = threadIdx.x;
    if (t < W4) {
        reinterpret_cast<fx4*>(sL)[t] =
            reinterpret_cast<const fx4*>(lrow)[t];
    } else if (t < 2 * W4) {
        reinterpret_cast<fx4*>(sR)[t - W4] =
            reinterpret_cast<const fx4*>(rrow)[t - W4];
    }
    __syncthreads();

    // out[c][d][h][w] = ((c*D + d)*H + h)*W + w
    float* obase = out + ((size_t)c * D * H + h) * W;

    const int total = D * W4;          // 5120 float4 for this (c,h)
    for (int idx = t; idx < total; idx += BLOCK) {
        const int d  = idx / W4;       // compile-time divisor
        const int w4 = idx - d * W4;
        const int w  = w4 * 4;

        const fx4 l = reinterpret_cast<const fx4*>(sL)[w4];

        const int i0 = w - d;
        const float r0 = (i0     >= 0) ? sR[i0]     : 0.0f;
        const float r1 = (i0 + 1 >= 0) ? sR[i0 + 1] : 0.0f;
        const float r2 = (i0 + 2 >= 0) ? sR[i0 + 2] : 0.0f;
        const float r3 = (i0 + 3 >= 0) ? sR[i0 + 3] : 0.0f;

        fx4 o;
        o.x = fminf(fmaxf(l.x * r0, -CLAMPV), CLAMPV);
        o.y = fminf(fmaxf(l.y * r1, -CLAMPV), CLAMPV);
        o.z = fminf(fmaxf(l.z * r2, -CLAMPV), CLAMPV);
        o.w = fminf(fmaxf(l.w * r3, -CLAMPV), CLAMPV);

        __builtin_nontemporal_store(o,
            reinterpret_cast<fx4*>(obase + (size_t)d * H * W + w));
    }
}

extern "C" void kernel_launch(void* const* d_in, const int* in_sizes, int n_in,
                              void* d_out, int out_size, void* d_ws, size_t ws_size,
                              hipStream_t stream) {
    const float* left  = (const float*)d_in[0];
    const float* right = (const float*)d_in[1];
    float* out = (float*)d_out;

    const int D = out_size / in_sizes[0];   // 64 with the fixed setup

    dim3 grid(C * H, 1, 1);                 // 5120 blocks, one per (c,h)
    dim3 block(BLOCK, 1, 1);
    costvol_kernel<<<grid, block, 0, stream>>>(left, right, out, D);
}